// Round 2
// baseline (2635.604 us; speedup 1.0000x reference)
//
#include <hip/hip_runtime.h>

// LSTM_77893526880768: B=T=F=H=256.  256 independent row-chains, 255 steps.
//
// v11 = v9 compute + v9 protocol (proven 1219us) + 2-chain latency hiding.
//
// Evidence (10 rounds):
//   v9 (barrier + SYSTEM RMW flags): 4.78us/step.  v10 (barrier-free,
//   per-wave volatile flags): 5.14us/step, WRITE_SIZE +1.5MB (sc0 flags
//   write through).  Protocol FLAVOR is a <10% effect => the step cost is
//   the serial latency chain itself (store drain -> flag propagate ->
//   detect -> L2 h load -> MFMA -> EW) at low-occupancy clocks.  v11 hides
//   it instead of shrinking it: the Wh LDS slice depends only on the COLUMN
//   range, so one WG serves its 32-col slice for TWO row-groups (x and x+4),
//   alternating phases.  Each chain's post->wait gap now spans the other
//   chain's full compute phase, covering most of the protocol latency.
//   Wall per step: (compute + latency) -> (2*compute + residual).
//
//   Placement: grid (8,8), linear id = x + 8*cg, XCD = linear%8 = x (MI355X
//   heuristic) => the 8 cg-peers of chain-set x share XCD x.  WGs x>=4 exit
//   immediately (32 live WGs on XCDs 0..3).  Runtime XCC_ID exchange
//   verifies co-location; falls back to the v7-proven cross-XCD protocol
//   (RELEASE wbl2 post / acquire-inv consume) per chain-set if not.
//   Chains are independent => correctness is placement-independent.
//
//   Protocol per chain phase (v9-proven, fast path): P prefetch -> tid0
//   polls flags[t][rg]==8 (RELAXED SYSTEM + s_sleep) -> __syncthreads ->
//   volatile (sc0) h loads probing the shared L2 -> MFMA -> EW -> plain h
//   stores -> __syncthreads (per-wave vmcnt drain into L2) -> tid0 RMW
//   flags[t+1][rg] (RELAXED; RELEASE=wbl2 on slow path).  t=0 skips the
//   read (h_0 = 0) => Hbuf needs no memset.  flags[t][rg] is shared by both
//   chains (different rg) -- disjoint ints.
//
//   64 KB LDS weights (v5-verified layout) serve BOTH chains.  All 4 gates
//   per lane via shfl_xor(8).  c in fp32 regs, creg[2] chains, ch-loop
//   force-unrolled so indexing stays static (no scratch).
//
// Workspace layout:
//   [0, 16K)        flags int[255][8] + xcd_tab int[64] @ +8K (memset 0)
//   [16K, 16K+256K) Hbuf bf16[2][256][256] (uninit; never read before write)
//   [0, 512K)       WxT bf16   (live only until precompute finishes)
//   [512K, 1M)      WhT bf16
//   [1M, 1M+4K)     bcat fp32
//   [1M+4K, ...)    P bf16  [t][rg16][n][16] = 133,693,440 B

#define STEPS 255

typedef short bf16x8 __attribute__((ext_vector_type(8)));
typedef short bf16x4 __attribute__((ext_vector_type(4)));
typedef float f32x4  __attribute__((ext_vector_type(4)));

__device__ inline unsigned short f2bf(float f) {
  unsigned int u = __float_as_uint(f);
  unsigned int r = (u + 0x7FFFu + ((u >> 16) & 1u)) >> 16;  // RNE
  return (unsigned short)r;
}
__device__ inline float bf2f(unsigned short s) {
  return __uint_as_float(((unsigned int)s) << 16);
}
__device__ inline float sig_f(float x) {
  float e = exp2f(-1.442695041f * x);
  return __builtin_amdgcn_rcpf(1.0f + e);
}
__device__ inline float tanh_f(float x) {
  float e = exp2f(-2.885390082f * x);
  return 2.0f * __builtin_amdgcn_rcpf(1.0f + e) - 1.0f;
}

// ---------- prep: W transpose (W[k][j] fp32 -> WT[g*256+j][k] bf16) ----------
__global__ __launch_bounds__(256) void lstm_prep_w(
    const float* __restrict__ m0, const float* __restrict__ m1,
    const float* __restrict__ m2, const float* __restrict__ m3,
    const float* __restrict__ m4, const float* __restrict__ m5,
    const float* __restrict__ m6, const float* __restrict__ m7,
    unsigned short* __restrict__ WxT, unsigned short* __restrict__ WhT) {
  const float* mats[8] = {m0, m1, m2, m3, m4, m5, m6, m7};
  int mat = blockIdx.z;
  const float* W = mats[mat];
  unsigned short* out = (mat < 4 ? WxT : WhT) + (size_t)(mat & 3) * 256 * 256;
  int kblk = blockIdx.x * 32, jblk = blockIdx.y * 32;
  __shared__ float tile[32][33];
  int tx = threadIdx.x & 31, ty = threadIdx.x >> 5;
#pragma unroll
  for (int i = 0; i < 4; ++i) {
    int kk = ty + i * 8;
    tile[kk][tx] = W[(size_t)(kblk + kk) * 256 + jblk + tx];
  }
  __syncthreads();
#pragma unroll
  for (int i = 0; i < 4; ++i) {
    int jj = ty + i * 8;
    out[(size_t)(jblk + jj) * 256 + kblk + tx] = f2bf(tile[tx][jj]);
  }
}

// ---------- prep: bias fold ----------
__global__ void lstm_prep_b(
    const float* __restrict__ bx0, const float* __restrict__ bx1,
    const float* __restrict__ bx2, const float* __restrict__ bx3,
    const float* __restrict__ bh0, const float* __restrict__ bh1,
    const float* __restrict__ bh2, const float* __restrict__ bh3,
    float* __restrict__ bcat) {
  const float* bx[4] = {bx0, bx1, bx2, bx3};
  const float* bh[4] = {bh0, bh1, bh2, bh3};
  int i = blockIdx.x * 256 + threadIdx.x;
  int g = i >> 8, j = i & 255;
  bcat[i] = bx[g][j] + bh[g][j];
}

// ---------- precompute: P[t][rg16][n][rl] = bcat[n] + sum_k x[r,t,k] Wx[k,n] ----------
// grid (255, 2): blockIdx.y selects 8 of the 16 n-blocks (x-frags duplicated).
__global__ __launch_bounds__(256, 1) void lstm_precompute(
    const float* __restrict__ x, const unsigned short* __restrict__ WxT,
    const float* __restrict__ bcat, unsigned short* __restrict__ P) {
  int t = blockIdx.x;
  int tid = threadIdx.x;
  int w = tid >> 6, lane = tid & 63, q = lane >> 4, cl = lane & 15;
  int rbase = w * 64;

  bf16x8 bfrag[8][4];
#pragma unroll
  for (int kt = 0; kt < 8; ++kt) {
    int k0 = kt * 32 + q * 8;
#pragma unroll
    for (int rt = 0; rt < 4; ++rt) {
      const float* xp = x + (((size_t)(rbase + rt * 16 + cl) * 256 + t) * 256 + k0);
      f32x4 lo = *(const f32x4*)xp;
      f32x4 hi = *(const f32x4*)(xp + 4);
      bf16x8 bv;
      bv[0] = (short)f2bf(lo[0]); bv[1] = (short)f2bf(lo[1]);
      bv[2] = (short)f2bf(lo[2]); bv[3] = (short)f2bf(lo[3]);
      bv[4] = (short)f2bf(hi[0]); bv[5] = (short)f2bf(hi[1]);
      bv[6] = (short)f2bf(hi[2]); bv[7] = (short)f2bf(hi[3]);
      bfrag[kt][rt] = bv;
    }
  }

  for (int nbi = 0; nbi < 8; ++nbi) {
    int nblk = (blockIdx.y * 8 + nbi) * 64;
    f32x4 acc[4][4];
#pragma unroll
    for (int a = 0; a < 4; ++a)
#pragma unroll
      for (int b = 0; b < 4; ++b) acc[a][b] = f32x4{0.f, 0.f, 0.f, 0.f};

#pragma unroll
    for (int kt = 0; kt < 8; ++kt) {
      int k0 = kt * 32 + q * 8;
      bf16x8 afrag[4];
#pragma unroll
      for (int mt = 0; mt < 4; ++mt)
        afrag[mt] = *(const bf16x8*)(WxT + (size_t)(nblk + mt * 16 + cl) * 256 + k0);
#pragma unroll
      for (int mt = 0; mt < 4; ++mt)
#pragma unroll
        for (int rt = 0; rt < 4; ++rt)
          acc[mt][rt] = __builtin_amdgcn_mfma_f32_16x16x32_bf16(
              afrag[mt], bfrag[kt][rt], acc[mt][rt], 0, 0, 0);
    }
#pragma unroll
    for (int mt = 0; mt < 4; ++mt) {
#pragma unroll
      for (int reg = 0; reg < 4; ++reg) {
        int n = nblk + mt * 16 + q * 4 + reg;
        float bb = bcat[n];
#pragma unroll
        for (int rt = 0; rt < 4; ++rt) {
          int rg16 = w * 4 + rt;  // = r>>4
          P[(((size_t)t * 16 + rg16) * 1024 + n) * 16 + cl] = f2bf(acc[mt][rt][reg] + bb);
        }
      }
    }
  }
}

// ---------- recurrent v11: 2 chains per WG, v9 protocol per chain phase ----------
__global__ __launch_bounds__(256, 1) void lstm_recurrent(
    const unsigned short* __restrict__ WhT,
    const unsigned short* __restrict__ P,
    unsigned short* Hbuf, int* flags, int* xcd_tab,
    float* __restrict__ out) {
  // Weight fragments, MFMA B-layout, exactly 64 KB (v5-verified):
  __shared__ bf16x8 wlds[4][2][8][64];

  int x = blockIdx.x;   // chain-set: handles rg = x and rg = x+4
  int cg = blockIdx.y;  // cols [cg*32, cg*32+32)
  if (x >= 4) return;   // 32 live WGs; linear id = x+8*cg => XCD x (heuristic)

  int tid = threadIdx.x;
  int w = tid >> 6, lane = tid & 63, q = lane >> 4, cl = lane & 15;
  int jglob = cg * 32 + w * 8 + (cl & 7);

  // ---- one-time XCD exchange among the 8 cg-peers of this chain-set
  int* same_lds = (int*)&wlds[0][0][0][0];
  if (tid == 0) {
    unsigned xcc;
    asm volatile("s_getreg_b32 %0, hwreg(HW_REG_XCC_ID)" : "=s"(xcc));
    __hip_atomic_store(&xcd_tab[x * 8 + cg], (int)xcc + 1,
                       __ATOMIC_RELEASE, __HIP_MEMORY_SCOPE_SYSTEM);
    int v0 = 0, samev = 1;
    for (int j = 0; j < 8; ++j) {
      int v;
      while ((v = __hip_atomic_load(&xcd_tab[x * 8 + j],
                                    __ATOMIC_ACQUIRE, __HIP_MEMORY_SCOPE_SYSTEM)) == 0)
        __builtin_amdgcn_s_sleep(1);
      if (j == 0) v0 = v;
      else if (v != v0) samev = 0;
    }
    same_lds[0] = samev;
  }
  __syncthreads();
  int same = same_lds[0];
  __syncthreads();

  // ---- stage weights into LDS (once): 4096 16B-chunks, 16 per thread.
  // Column-slice only => the SAME 64 KB serves both chains.
  for (int i = 0; i < 16; ++i) {
    int idx = tid + i * 256;
    int sw = idx >> 10, snt = (idx >> 9) & 1, skt = (idx >> 6) & 7, sl = idx & 63;
    int sq = sl >> 4, scl = sl & 15;
    int gate = snt * 2 + (scl >> 3);
    int col = cg * 32 + sw * 8 + (scl & 7);
    int k0 = skt * 32 + sq * 8;
    (&wlds[0][0][0][0])[idx] = *(const bf16x8*)(WhT + (size_t)(gate * 256 + col) * 256 + k0);
  }
  __syncthreads();

  float creg[2][2][4] = {{{0.f, 0.f, 0.f, 0.f}, {0.f, 0.f, 0.f, 0.f}},
                         {{0.f, 0.f, 0.f, 0.f}, {0.f, 0.f, 0.f, 0.f}}};
  unsigned short* H0 = Hbuf;             // [256][256] bf16 (uninit; t=0 skips read)
  unsigned short* H1 = Hbuf + 65536;

  for (int t = 0; t < STEPS; ++t) {
    bool last = (t == STEPS - 1);
#pragma unroll
    for (int ch = 0; ch < 2; ++ch) {     // MUST unroll: creg[ch] static index
      int rg = x + ch * 4;
      int r0 = rg * 32;

      // P prefetch (independent of peers) before the flag wait.
      bf16x4 pv[2][4];
#pragma unroll
      for (int rt = 0; rt < 2; ++rt) {
        int rg16 = rg * 2 + rt;
#pragma unroll
        for (int g = 0; g < 4; ++g)
          pv[rt][g] = *(const bf16x4*)(
              P + (((size_t)t * 16 + rg16) * 1024 + g * 256 + jglob) * 16 + q * 4);
      }

      bf16x8 afrag[2][8];
      if (t > 0) {
        if (tid == 0) {
          const int* fp = flags + t * 8 + rg;  // == 8 when all cg-peers posted t
          while (__hip_atomic_load(fp, __ATOMIC_RELAXED, __HIP_MEMORY_SCOPE_SYSTEM) < 8)
            __builtin_amdgcn_s_sleep(1);
          if (!same)  // cross-XCD: one cache-wide acquire inv (v7-proven)
            __builtin_amdgcn_fence(__ATOMIC_ACQUIRE, "");
        }
        __syncthreads();

        const unsigned short* Hb = (t & 1) ? H1 : H0;
        if (same) {
          // FAST: peers share this XCD's L2; sc0 (volatile) loads probe the
          // shared L2 where peers' vmcnt-drained plain stores are ack'd.
          const volatile bf16x8* Hv = (const volatile bf16x8*)Hb;
#pragma unroll
          for (int rt = 0; rt < 2; ++rt)
#pragma unroll
            for (int kt = 0; kt < 8; ++kt)
              afrag[rt][kt] = Hv[((size_t)(r0 + rt * 16 + cl) * 256 + kt * 32 + q * 8) >> 3];
        } else {
          // SLOW (v7-proven): plain loads post-inv.
#pragma unroll
          for (int rt = 0; rt < 2; ++rt)
#pragma unroll
            for (int kt = 0; kt < 8; ++kt)
              afrag[rt][kt] = *(const bf16x8*)(Hb + (size_t)(r0 + rt * 16 + cl) * 256 + kt * 32 + q * 8);
        }
      } else {
        // t = 0: h_0 = 0 -> no read, no wait (Hbuf may be uninitialized).
#pragma unroll
        for (int rt = 0; rt < 2; ++rt)
#pragma unroll
          for (int kt = 0; kt < 8; ++kt)
            afrag[rt][kt] = (bf16x8){0, 0, 0, 0, 0, 0, 0, 0};
      }

      // ---- MFMA: 2 row-tiles x 2 n-tiles ({i,f},{g,o} x 8 cols) x 8 k-tiles
      f32x4 acc[2][2];
#pragma unroll
      for (int rt = 0; rt < 2; ++rt)
#pragma unroll
        for (int nt = 0; nt < 2; ++nt) acc[rt][nt] = f32x4{0.f, 0.f, 0.f, 0.f};
#pragma unroll
      for (int kt = 0; kt < 8; ++kt)
#pragma unroll
        for (int rt = 0; rt < 2; ++rt)
#pragma unroll
          for (int nt = 0; nt < 2; ++nt)
            acc[rt][nt] = __builtin_amdgcn_mfma_f32_16x16x32_bf16(
                afrag[rt][kt], wlds[w][nt][kt][lane], acc[rt][nt], 0, 0, 0);

      // ---- elementwise: lane cl holds (cl<8 ? {i,g} : {f,o}); shfl_xor(8).
      unsigned short* Hw = ((t & 1) ? H0 : H1);
      bool lo = (cl & 8) == 0;
#pragma unroll
      for (int rt = 0; rt < 2; ++rt) {
#pragma unroll
        for (int e = 0; e < 4; ++e) {
          float own0 = acc[rt][0][e], oth0 = __shfl_xor(own0, 8, 64);
          float own1 = acc[rt][1][e], oth1 = __shfl_xor(own1, 8, 64);
          float pi = (lo ? own0 : oth0) + bf2f((unsigned short)pv[rt][0][e]);
          float pf = (lo ? oth0 : own0) + bf2f((unsigned short)pv[rt][1][e]);
          float pg = (lo ? own1 : oth1) + bf2f((unsigned short)pv[rt][2][e]);
          float po = (lo ? oth1 : own1) + bf2f((unsigned short)pv[rt][3][e]);
          float ig = sig_f(pi), fg = sig_f(pf), gg = tanh_f(pg), og = sig_f(po);
          float cn = fg * creg[ch][rt][e] + ig * gg;
          creg[ch][rt][e] = cn;
          float hn = og * tanh_f(cn);
          int r = r0 + rt * 16 + q * 4 + e;
          if (lo) {
            if (!last) {
              Hw[(size_t)r * 256 + jglob] = f2bf(hn);  // plain store -> shared L2
            } else {
              out[(size_t)r * 256 + jglob] = hn;
              out[65536 + (size_t)r * 256 + jglob] = cn;
            }
          }
        }
      }

      if (!last) {
        // All waves' h stores are vmcnt-drained into L2 by this barrier
        // (compiler emits per-wave s_waitcnt vmcnt(0) before s_barrier).
        __syncthreads();
        if (tid == 0) {
          if (same)
            // FAST: peers consume from the shared L2; flag RMW needs no wbl2.
            __hip_atomic_fetch_add(flags + (t + 1) * 8 + rg, 1,
                                   __ATOMIC_RELAXED, __HIP_MEMORY_SCOPE_SYSTEM);
          else
            // SLOW (v7-proven): RELEASE = wbl2 publishes L2-dirty h first.
            __hip_atomic_fetch_add(flags + (t + 1) * 8 + rg, 1,
                                   __ATOMIC_RELEASE, __HIP_MEMORY_SCOPE_SYSTEM);
        }
      }
    }  // ch
  }  // t
}

extern "C" void kernel_launch(void* const* d_in, const int* in_sizes, int n_in,
                              void* d_out, int out_size, void* d_ws, size_t ws_size,
                              hipStream_t stream) {
  const float* x = (const float*)d_in[0];
  const float* wx0 = (const float*)d_in[1];
  const float* wx1 = (const float*)d_in[5];
  const float* wx2 = (const float*)d_in[9];
  const float* wx3 = (const float*)d_in[13];
  const float* wh0 = (const float*)d_in[3];
  const float* wh1 = (const float*)d_in[7];
  const float* wh2 = (const float*)d_in[11];
  const float* wh3 = (const float*)d_in[15];
  const float* bx0 = (const float*)d_in[2];
  const float* bx1 = (const float*)d_in[6];
  const float* bx2 = (const float*)d_in[10];
  const float* bx3 = (const float*)d_in[14];
  const float* bh0 = (const float*)d_in[4];
  const float* bh1 = (const float*)d_in[8];
  const float* bh2 = (const float*)d_in[12];
  const float* bh3 = (const float*)d_in[16];

  char* ws = (char*)d_ws;
  unsigned short* WxT = (unsigned short*)(ws + 0);          // dead after precompute
  unsigned short* WhT = (unsigned short*)(ws + 524288);
  float* bcat = (float*)(ws + 1048576);
  unsigned short* P = (unsigned short*)(ws + 1052672);      // [t][rg16][n][16] bf16
  int* flags = (int*)(ws + 0);                              // int[255][8], overlays WxT
  int* xcd_tab = (int*)(ws + 8192);                         // 64 ints (32 used)
  unsigned short* Hbuf = (unsigned short*)(ws + 16384);     // [2][256][256] bf16

  lstm_prep_w<<<dim3(8, 8, 8), 256, 0, stream>>>(wx0, wx1, wx2, wx3,
                                                 wh0, wh1, wh2, wh3, WxT, WhT);
  lstm_prep_b<<<4, 256, 0, stream>>>(bx0, bx1, bx2, bx3, bh0, bh1, bh2, bh3, bcat);
  lstm_precompute<<<dim3(255, 2), 256, 0, stream>>>(x, WxT, bcat, P);
  hipMemsetAsync(ws, 0, 16384, stream);  // flags + xcd_tab only (Hbuf never pre-read)
  lstm_recurrent<<<dim3(8, 8), 256, 0, stream>>>(WhT, P, Hbuf, flags, xcd_tab,
                                                 (float*)d_out);
}

// Round 3
// 1587.146 us; speedup vs baseline: 1.6606x; 1.6606x over previous
//
#include <hip/hip_runtime.h>

// LSTM_77893526880768: B=T=F=H=256.  256 independent row-chains, 255 steps.
//
// v12: cross-WG sync ELIMINATED.  Evidence from v9/v10/v11: per-phase cost
// ~4.7us (~11.5K cy @2.4GHz, clock confirmed via MfmaUtil arithmetic) is a
// FIXED serial cost of any cross-WG round (invariant across protocol flavor;
// not elapsed-time-dependent: v11's pre-posted flags still cost full L).
// So v12 makes the recurrence intra-WG:
//
//   16 WGs x 512 threads (8 waves, 2 waves/SIMD, 1 WG/CU).  WG x owns rows
//   [16x,16x+16) x ALL 256 cols.  Wh (4 gates x 256 cols x 256 k bf16 =
//   512 KB) is CU-resident:
//     - gates i,f,g: VGPR-resident B-frags, 48 tiles = 192 VGPRs/wave
//       (wave w holds col-blocks {2w,2w+1}, statically indexed -- rule #20)
//     - gate o: LDS, 16 tiles = 128 KB (same proven conflict-free layout as
//       v5's wlds)
//   h: LDS double buffer [2][16][256] bf16 = 16 KB (total LDS 144 KB <= 160).
//   Per step: 8 kt x 4 gates x 2 blocks MFMA -> EW (all 4 gates lane-local,
//   no shuffles) -> h write -> ONE __syncthreads.  No flags, no atomics.
//
//   h A-read swizzle: byte ^= ((row&7)<<4) breaks the 512B-row-stride bank
//   conflict (guide G4); read and write apply the same XOR (both-sides rule).
//
// Workspace layout (unchanged; flags/Hbuf areas now unused):
//   [0, 512K)       WxT bf16   (live only until precompute finishes)
//   [512K, 1M)      WhT bf16
//   [1M, 1M+4K)     bcat fp32
//   [1M+4K, ...)    P bf16  [t][rg16][n][16] = 133,693,440 B

#define STEPS 255

typedef short bf16x8 __attribute__((ext_vector_type(8)));
typedef short bf16x4 __attribute__((ext_vector_type(4)));
typedef float f32x4  __attribute__((ext_vector_type(4)));

__device__ inline unsigned short f2bf(float f) {
  unsigned int u = __float_as_uint(f);
  unsigned int r = (u + 0x7FFFu + ((u >> 16) & 1u)) >> 16;  // RNE
  return (unsigned short)r;
}
__device__ inline float bf2f(unsigned short s) {
  return __uint_as_float(((unsigned int)s) << 16);
}
__device__ inline float sig_f(float x) {
  float e = exp2f(-1.442695041f * x);
  return __builtin_amdgcn_rcpf(1.0f + e);
}
__device__ inline float tanh_f(float x) {
  float e = exp2f(-2.885390082f * x);
  return 2.0f * __builtin_amdgcn_rcpf(1.0f + e) - 1.0f;
}

// ---------- prep: W transpose (W[k][j] fp32 -> WT[g*256+j][k] bf16) ----------
__global__ __launch_bounds__(256) void lstm_prep_w(
    const float* __restrict__ m0, const float* __restrict__ m1,
    const float* __restrict__ m2, const float* __restrict__ m3,
    const float* __restrict__ m4, const float* __restrict__ m5,
    const float* __restrict__ m6, const float* __restrict__ m7,
    unsigned short* __restrict__ WxT, unsigned short* __restrict__ WhT) {
  const float* mats[8] = {m0, m1, m2, m3, m4, m5, m6, m7};
  int mat = blockIdx.z;
  const float* W = mats[mat];
  unsigned short* out = (mat < 4 ? WxT : WhT) + (size_t)(mat & 3) * 256 * 256;
  int kblk = blockIdx.x * 32, jblk = blockIdx.y * 32;
  __shared__ float tile[32][33];
  int tx = threadIdx.x & 31, ty = threadIdx.x >> 5;
#pragma unroll
  for (int i = 0; i < 4; ++i) {
    int kk = ty + i * 8;
    tile[kk][tx] = W[(size_t)(kblk + kk) * 256 + jblk + tx];
  }
  __syncthreads();
#pragma unroll
  for (int i = 0; i < 4; ++i) {
    int jj = ty + i * 8;
    out[(size_t)(jblk + jj) * 256 + kblk + tx] = f2bf(tile[tx][jj]);
  }
}

// ---------- prep: bias fold ----------
__global__ void lstm_prep_b(
    const float* __restrict__ bx0, const float* __restrict__ bx1,
    const float* __restrict__ bx2, const float* __restrict__ bx3,
    const float* __restrict__ bh0, const float* __restrict__ bh1,
    const float* __restrict__ bh2, const float* __restrict__ bh3,
    float* __restrict__ bcat) {
  const float* bx[4] = {bx0, bx1, bx2, bx3};
  const float* bh[4] = {bh0, bh1, bh2, bh3};
  int i = blockIdx.x * 256 + threadIdx.x;
  int g = i >> 8, j = i & 255;
  bcat[i] = bx[g][j] + bh[g][j];
}

// ---------- precompute: P[t][rg16][n][rl] = bcat[n] + sum_k x[r,t,k] Wx[k,n] ----------
// grid (255, 2): blockIdx.y selects 8 of the 16 n-blocks (x-frags duplicated).
__global__ __launch_bounds__(256, 1) void lstm_precompute(
    const float* __restrict__ x, const unsigned short* __restrict__ WxT,
    const float* __restrict__ bcat, unsigned short* __restrict__ P) {
  int t = blockIdx.x;
  int tid = threadIdx.x;
  int w = tid >> 6, lane = tid & 63, q = lane >> 4, cl = lane & 15;
  int rbase = w * 64;

  bf16x8 bfrag[8][4];
#pragma unroll
  for (int kt = 0; kt < 8; ++kt) {
    int k0 = kt * 32 + q * 8;
#pragma unroll
    for (int rt = 0; rt < 4; ++rt) {
      const float* xp = x + (((size_t)(rbase + rt * 16 + cl) * 256 + t) * 256 + k0);
      f32x4 lo = *(const f32x4*)xp;
      f32x4 hi = *(const f32x4*)(xp + 4);
      bf16x8 bv;
      bv[0] = (short)f2bf(lo[0]); bv[1] = (short)f2bf(lo[1]);
      bv[2] = (short)f2bf(lo[2]); bv[3] = (short)f2bf(lo[3]);
      bv[4] = (short)f2bf(hi[0]); bv[5] = (short)f2bf(hi[1]);
      bv[6] = (short)f2bf(hi[2]); bv[7] = (short)f2bf(hi[3]);
      bfrag[kt][rt] = bv;
    }
  }

  for (int nbi = 0; nbi < 8; ++nbi) {
    int nblk = (blockIdx.y * 8 + nbi) * 64;
    f32x4 acc[4][4];
#pragma unroll
    for (int a = 0; a < 4; ++a)
#pragma unroll
      for (int b = 0; b < 4; ++b) acc[a][b] = f32x4{0.f, 0.f, 0.f, 0.f};

#pragma unroll
    for (int kt = 0; kt < 8; ++kt) {
      int k0 = kt * 32 + q * 8;
      bf16x8 afrag[4];
#pragma unroll
      for (int mt = 0; mt < 4; ++mt)
        afrag[mt] = *(const bf16x8*)(WxT + (size_t)(nblk + mt * 16 + cl) * 256 + k0);
#pragma unroll
      for (int mt = 0; mt < 4; ++mt)
#pragma unroll
        for (int rt = 0; rt < 4; ++rt)
          acc[mt][rt] = __builtin_amdgcn_mfma_f32_16x16x32_bf16(
              afrag[mt], bfrag[kt][rt], acc[mt][rt], 0, 0, 0);
    }
#pragma unroll
    for (int mt = 0; mt < 4; ++mt) {
#pragma unroll
      for (int reg = 0; reg < 4; ++reg) {
        int n = nblk + mt * 16 + q * 4 + reg;
        float bb = bcat[n];
#pragma unroll
        for (int rt = 0; rt < 4; ++rt) {
          int rg16 = w * 4 + rt;  // = r>>4
          P[(((size_t)t * 16 + rg16) * 1024 + n) * 16 + cl] = f2bf(acc[mt][rt][reg] + bb);
        }
      }
    }
  }
}

// ---------- recurrent v12: fully intra-WG, weights CU-resident ----------
// WG x: rows [16x, 16x+16), all 256 cols.  8 waves; wave w owns col-blocks
// {2w, 2w+1} (16 cols each) for all 4 gates.  Gates i,f,g in VGPRs, gate o
// in LDS.  h in LDS double buffer.  One __syncthreads per step.
__global__ __launch_bounds__(512, 2) void lstm_recurrent(
    const unsigned short* __restrict__ WhT,
    const unsigned short* __restrict__ P,
    float* __restrict__ out) {
  // o-gate B-frags: [wave][block][kt][lane] bf16x8 = 128 KB (v5-proven layout)
  __shared__ bf16x8 o_w[8][2][8][64];
  // h double buffer, XOR-swizzled: byte ^= ((row&7)<<4).  16 KB.
  __shared__ unsigned short hbuf[2][16 * 256];

  int tid = threadIdx.x;
  int w = tid >> 6, lane = tid & 63, q = lane >> 4, cl = lane & 15;
  int x = blockIdx.x;  // rows [16x, 16x+16)

  // ---- stage o-gate tiles into LDS: 8192 16B-chunks, 16 per thread
  for (int i = 0; i < 16; ++i) {
    int idx = tid + i * 512;
    int sw = idx >> 10, sb = (idx >> 9) & 1, skt = (idx >> 6) & 7, sl = idx & 63;
    int sq = sl >> 4, scl = sl & 15;
    int col = (2 * sw + sb) * 16 + scl;
    int k0 = skt * 32 + sq * 8;
    o_w[sw][sb][skt][sl] = *(const bf16x8*)(WhT + (size_t)(3 * 256 + col) * 256 + k0);
  }

  // ---- i,f,g gate tiles into VGPRs (static indexing only -- rule #20)
  bf16x8 wreg[2][3][8];  // [block][gate][kt] = 48 frags = 192 VGPRs
#pragma unroll
  for (int b = 0; b < 2; ++b)
#pragma unroll
    for (int g = 0; g < 3; ++g)
#pragma unroll
      for (int kt = 0; kt < 8; ++kt) {
        int col = (2 * w + b) * 16 + cl;
        wreg[b][g][kt] =
            *(const bf16x8*)(WhT + (size_t)(g * 256 + col) * 256 + kt * 32 + q * 8);
      }

  // ---- zero h buffer 0 (h_0 = 0); swizzle irrelevant for zeros
  for (int i = tid; i < 2048; i += 512) ((unsigned int*)&hbuf[0][0])[i] = 0;
  __syncthreads();

  // A-read base (t-independent): row = cl, k-offset q*16 within kt-block,
  // swizzled.  Per kt: byte = abase ^ (kt*64)  (bits 6-8 of abase are the
  // swizzle's bit 6 only; kt*64 XOR is exact -- verified bit-disjointness).
  int abase = cl * 512 + ((q * 16) ^ ((cl & 7) << 4));

  float creg[2][4] = {{0.f, 0.f, 0.f, 0.f}, {0.f, 0.f, 0.f, 0.f}};

  for (int t = 0; t < STEPS; ++t) {
    int rb = t & 1;           // read buffer index
    bool lastt = (t == STEPS - 1);

    // P loads for both col-blocks (issued early; consumed after MFMA)
    bf16x4 pv[2][4];
#pragma unroll
    for (int b = 0; b < 2; ++b) {
      int colb = 32 * w + b * 16 + cl;
#pragma unroll
      for (int g = 0; g < 4; ++g)
        pv[b][g] = *(const bf16x4*)(
            P + (((size_t)t * 16 + x) * 1024 + g * 256 + colb) * 16 + q * 4);
    }

    const unsigned short* hr = &hbuf[rb][0];
    unsigned short* hw = &hbuf[rb ^ 1][0];

#pragma unroll
    for (int b = 0; b < 2; ++b) {
      f32x4 acc[4];
#pragma unroll
      for (int g = 0; g < 4; ++g) acc[g] = f32x4{0.f, 0.f, 0.f, 0.f};

#pragma unroll
      for (int kt = 0; kt < 8; ++kt) {
        bf16x8 af = *(const bf16x8*)(hr + ((abase ^ (kt * 64)) >> 1));
        acc[0] = __builtin_amdgcn_mfma_f32_16x16x32_bf16(af, wreg[b][0][kt], acc[0], 0, 0, 0);
        acc[1] = __builtin_amdgcn_mfma_f32_16x16x32_bf16(af, wreg[b][1][kt], acc[1], 0, 0, 0);
        acc[2] = __builtin_amdgcn_mfma_f32_16x16x32_bf16(af, wreg[b][2][kt], acc[2], 0, 0, 0);
        acc[3] = __builtin_amdgcn_mfma_f32_16x16x32_bf16(af, o_w[w][b][kt][lane], acc[3], 0, 0, 0);
      }

      // EW: lane (q,cl) owns rows q*4+e, col 32w+b*16+cl; all 4 gates local.
      int colb = 32 * w + b * 16 + cl;
#pragma unroll
      for (int e = 0; e < 4; ++e) {
        float pi = acc[0][e] + bf2f((unsigned short)pv[b][0][e]);
        float pf = acc[1][e] + bf2f((unsigned short)pv[b][1][e]);
        float pg = acc[2][e] + bf2f((unsigned short)pv[b][2][e]);
        float po = acc[3][e] + bf2f((unsigned short)pv[b][3][e]);
        float ig = sig_f(pi), fg = sig_f(pf), gg = tanh_f(pg), og = sig_f(po);
        float cn = fg * creg[b][e] + ig * gg;
        creg[b][e] = cn;
        float hn = og * tanh_f(cn);
        int r = q * 4 + e;
        if (!lastt) {
          int wb = r * 512 + ((colb * 2) ^ ((r & 7) << 4));
          hw[wb >> 1] = f2bf(hn);
        } else {
          out[(size_t)(x * 16 + r) * 256 + colb] = hn;
          out[65536 + (size_t)(x * 16 + r) * 256 + colb] = cn;
        }
      }
    }

    __syncthreads();  // h(t+1) complete before step t+1 reads it
  }
}

extern "C" void kernel_launch(void* const* d_in, const int* in_sizes, int n_in,
                              void* d_out, int out_size, void* d_ws, size_t ws_size,
                              hipStream_t stream) {
  const float* x = (const float*)d_in[0];
  const float* wx0 = (const float*)d_in[1];
  const float* wx1 = (const float*)d_in[5];
  const float* wx2 = (const float*)d_in[9];
  const float* wx3 = (const float*)d_in[13];
  const float* wh0 = (const float*)d_in[3];
  const float* wh1 = (const float*)d_in[7];
  const float* wh2 = (const float*)d_in[11];
  const float* wh3 = (const float*)d_in[15];
  const float* bx0 = (const float*)d_in[2];
  const float* bx1 = (const float*)d_in[6];
  const float* bx2 = (const float*)d_in[10];
  const float* bx3 = (const float*)d_in[14];
  const float* bh0 = (const float*)d_in[4];
  const float* bh1 = (const float*)d_in[8];
  const float* bh2 = (const float*)d_in[12];
  const float* bh3 = (const float*)d_in[16];

  char* ws = (char*)d_ws;
  unsigned short* WxT = (unsigned short*)(ws + 0);          // dead after precompute
  unsigned short* WhT = (unsigned short*)(ws + 524288);
  float* bcat = (float*)(ws + 1048576);
  unsigned short* P = (unsigned short*)(ws + 1052672);      // [t][rg16][n][16] bf16

  lstm_prep_w<<<dim3(8, 8, 8), 256, 0, stream>>>(wx0, wx1, wx2, wx3,
                                                 wh0, wh1, wh2, wh3, WxT, WhT);
  lstm_prep_b<<<4, 256, 0, stream>>>(bx0, bx1, bx2, bx3, bh0, bh1, bh2, bh3, bcat);
  lstm_precompute<<<dim3(255, 2), 256, 0, stream>>>(x, WxT, bcat, P);
  lstm_recurrent<<<dim3(16), 512, 0, stream>>>(WhT, P, (float*)d_out);
}